// Round 1
// baseline (183.661 us; speedup 1.0000x reference)
//
#include <hip/hip_runtime.h>
#include <math.h>

#define B_ 64
#define S_ 512
#define N_ 24
#define H_ 768
#define C_ 6

// Kernel A: per-token projection to C=6 dims + atomic segment accumulation.
// One wave per token. W fragment held in registers (3 x 6 float4 per lane).
__global__ __launch_bounds__(256) void proj_seg_kernel(
    const float* __restrict__ lhs, const int* __restrict__ st,
    const float* __restrict__ W, float* __restrict__ segsum, int ntok) {
  const int lane = threadIdx.x & 63;
  const int gwave = (int)((blockIdx.x * blockDim.x + threadIdx.x) >> 6);
  const int nwaves = (int)((gridDim.x * blockDim.x) >> 6);

  // Load W fragments: lane holds W[c][k*256 + lane*4 .. +3] for k=0..2, c=0..5
  const float4* W4 = (const float4*)W;
  float4 w[3][C_];
#pragma unroll
  for (int k = 0; k < 3; ++k)
#pragma unroll
    for (int c = 0; c < C_; ++c)
      w[k][c] = W4[c * (H_ / 4) + k * 64 + lane];

  for (int t = gwave; t < ntok; t += nwaves) {
    const int b = t >> 9;   // t / 512
    const int s = t & 511;  // t % 512
    const int* stb = st + b * N_;
    if (s > stb[N_ - 1]) continue;  // token beyond last boundary: unused

    // smallest j with stb[j] >= s  (segment j covers (stb[j-1], stb[j]])
    int lo = 0, hi = N_ - 1;
    while (lo < hi) {
      int mid = (lo + hi) >> 1;
      if (stb[mid] < s) lo = mid + 1; else hi = mid;
    }

    const float4* x4 = (const float4*)(lhs + (size_t)t * H_);
    float acc[C_];
#pragma unroll
    for (int c = 0; c < C_; ++c) acc[c] = 0.0f;
#pragma unroll
    for (int k = 0; k < 3; ++k) {
      float4 x = x4[k * 64 + lane];  // wave reads 1 KiB contiguous
#pragma unroll
      for (int c = 0; c < C_; ++c)
        acc[c] += x.x * w[k][c].x + x.y * w[k][c].y +
                  x.z * w[k][c].z + x.w * w[k][c].w;
    }
    // wave-reduce each of the 6 partials to lane 0
#pragma unroll
    for (int c = 0; c < C_; ++c) {
      float v = acc[c];
      v += __shfl_down(v, 32, 64);
      v += __shfl_down(v, 16, 64);
      v += __shfl_down(v, 8, 64);
      v += __shfl_down(v, 4, 64);
      v += __shfl_down(v, 2, 64);
      v += __shfl_down(v, 1, 64);
      acc[c] = v;
    }
    if (lane == 0) {
      float* dst = segsum + ((size_t)b * N_ + lo) * C_;
#pragma unroll
      for (int c = 0; c < C_; ++c) atomicAdd(dst + c, acc[c]);
    }
  }
}

// Kernel B: mean, bias, sigmoid, const-override. One thread per output elem.
__global__ __launch_bounds__(256) void finalize_kernel(
    const float* __restrict__ segsum, const int* __restrict__ st,
    const float* __restrict__ bias, float* __restrict__ out) {
  int idx = blockIdx.x * blockDim.x + threadIdx.x;
  if (idx >= B_ * N_ * C_) return;
  int c = idx % C_;
  int j = (idx / C_) % N_;
  int b = idx / (N_ * C_);
  int end = st[b * N_ + j];
  int prev = (j == 0) ? -1 : st[b * N_ + j - 1];
  float len = (float)(end - prev);
  float logit = segsum[idx] / len + bias[c];
  float p = 1.0f / (1.0f + expf(-logit));
  if (end > 500) {
    float cl = (c < 3) ? 0.1f : (c == 3 ? 0.3f : (c == 4 ? 0.8f : 0.01f));
    float cm = (c < 3) ? 0.1f : (c == 3 ? 0.8f : (c == 4 ? 0.3f : 0.01f));
    p = (j == N_ - 1) ? cl : cm;
  }
  out[idx] = p;
}

extern "C" void kernel_launch(void* const* d_in, const int* in_sizes, int n_in,
                              void* d_out, int out_size, void* d_ws, size_t ws_size,
                              hipStream_t stream) {
  const float* lhs  = (const float*)d_in[0];  // [B,S,H] fp32
  const int*   st   = (const int*)d_in[1];    // [B,N] int32
  const float* W    = (const float*)d_in[2];  // [C,H] fp32
  const float* bias = (const float*)d_in[3];  // [C] fp32
  float* segsum = (float*)d_ws;               // [B,N,C] fp32 accumulators (36 KB)

  hipMemsetAsync(d_ws, 0, (size_t)B_ * N_ * C_ * sizeof(float), stream);
  proj_seg_kernel<<<2048, 256, 0, stream>>>(lhs, st, W, segsum, B_ * S_);
  finalize_kernel<<<(B_ * N_ * C_ + 255) / 256, 256, 0, stream>>>(
      segsum, st, bias, (float*)d_out);
}